// Round 1
// baseline (579.112 us; speedup 1.0000x reference)
//
#include <hip/hip_runtime.h>
#include <hip/hip_bf16.h>

// SubQAttention: B=4, H=16, T=1024, D=64, N_BINS=16, ROUTER_HIDDEN=128
// Stage 1: router_kernel  -> bucket_probs [B*T, 16]   (fp32, in ws)
// Stage 2: mask_kernel    -> causal&bucket bitmask [B*T, 16] uint64 (in ws)
// Stage 3: attn_kernel    -> flash-style fp32 attention with bitmask
//
// All fp32 (no fp32 MFMA on CDNA4 -> VALU). Router/sim must be fp32: the
// (sim > 0.05) comparator would flip bits under bf16 rounding.

#define B_ 4
#define H_ 16
#define T_ 1024
#define D_ 64
#define NB 16
#define RH 128

// ---------------- Stage 1: router (8 rows per block, 256 threads) ----------
// thread = (half, hidden_unit); each half accumulates 512 of the 1024 K-dims.
__global__ __launch_bounds__(256) void router_kernel(
    const float* __restrict__ kin, const float* __restrict__ W1,
    const float* __restrict__ b1, const float* __restrict__ W2,
    const float* __restrict__ b2, float* __restrict__ probs) {
  __shared__ float rows[8][1024];     // 32 KB: 8 k_flat rows
  __shared__ float part[8][2][RH];    // 8 KB: per-half partial dots
  __shared__ float hid[8][RH + 1];    // padded: (r+jj)%32 conflict-free
  __shared__ float logits[8][NB];

  const int tid = threadIdx.x;
  const int half = tid >> 7;          // 0/1: which 512-dim slice
  const int hu = tid & 127;           // hidden unit
  const int bb = blockIdx.x;          // 512 blocks
  const int b = bb >> 7;              // 128 blocks per batch (T/8)
  const int t0 = (bb & 127) << 3;

  // stage k_flat rows: k_flat[b,t,h*64+d] = k[b,h,t,d]
  for (int idx = tid; idx < 8 * 1024; idx += 256) {
    const int r = idx >> 10, i = idx & 1023;
    rows[r][i] = kin[(((size_t)(b * H_) + (i >> 6)) * T_ + (t0 + r)) * D_ + (i & 63)];
  }
  __syncthreads();

  float acc[8];
#pragma unroll
  for (int r = 0; r < 8; r++) acc[r] = 0.0f;
  const int ib = half << 9;
  for (int i0 = 0; i0 < 512; i0 += 8) {
#pragma unroll
    for (int u = 0; u < 8; u++) {
      const float w = W1[(size_t)(ib + i0 + u) * RH + hu];  // coalesced, L2-res
#pragma unroll
      for (int r = 0; r < 8; r++) acc[r] += rows[r][ib + i0 + u] * w;  // LDS bcast
    }
  }
#pragma unroll
  for (int r = 0; r < 8; r++) part[r][half][hu] = acc[r];
  __syncthreads();

  if (half == 0) {
#pragma unroll
    for (int r = 0; r < 8; r++)
      hid[r][hu] = tanhf(part[r][0][hu] + part[r][1][hu] + b1[hu]);
  }
  __syncthreads();

  if (tid < 128) {  // 8 rows x 16 bins
    const int r = tid >> 4, bin = tid & 15;
    float a = b2[bin];
#pragma unroll
    for (int jj = 0; jj < RH; jj++) a += hid[r][jj] * W2[jj * NB + bin];
    logits[r][bin] = a;
  }
  __syncthreads();

  if (tid < 8) {
    const int r = tid;
    float mx = -INFINITY;
#pragma unroll
    for (int bin = 0; bin < NB; bin++) mx = fmaxf(mx, logits[r][bin]);
    float e[NB];
    float s = 0.0f;
#pragma unroll
    for (int bin = 0; bin < NB; bin++) {
      e[bin] = expf(logits[r][bin] - mx);  // TEMPERATURE = 1
      s += e[bin];
    }
    const float inv = 1.0f / s;
    const size_t row = (size_t)(b * T_ + t0 + r) * NB;
#pragma unroll
    for (int bin = 0; bin < NB; bin++) probs[row + bin] = e[bin] * inv;
  }
}

// ---------------- Stage 2: bucket bitmask (one block per (b,i) row) --------
__global__ __launch_bounds__(256) void mask_kernel(
    const float* __restrict__ probs, unsigned long long* __restrict__ mask) {
  const int blk = blockIdx.x;  // b*T + i
  const int b = blk >> 10;
  const int i = blk & 1023;
  const int tid = threadIdx.x;

  float pi[NB];
#pragma unroll
  for (int kk = 0; kk < NB; kk++) pi[kk] = probs[(size_t)blk * NB + kk];

#pragma unroll
  for (int c = 0; c < 4; c++) {
    const int j = c * 256 + tid;
    const float* pj = probs + ((size_t)(b << 10) + j) * NB;
    float sim = 0.0f;
#pragma unroll
    for (int kk = 0; kk < NB; kk++) sim += pi[kk] * pj[kk];
    const bool ok = (j <= i) && (sim > 0.05f);   // causal & bucket
    const unsigned long long bal = __ballot(ok); // 64-bit wave mask
    if ((tid & 63) == 0)
      mask[((size_t)blk << 4) + (c * 4 + (tid >> 6))] = bal;
  }
}

// ---------------- Stage 3: attention -----------------------------------
// Block: 256 threads = 4 waves; handles (bh, q-tile of 64 rows).
// Wave w owns rows i0 = w*16 .. +15. Score phase: lane = key j.
// PV phase: lane = output dim d. K tile XOR-swizzled to kill the
// 32-way bank conflict on Ks[lane][d] reads; V/P column-indexed (free).
__global__ __launch_bounds__(256) void attn_kernel(
    const float* __restrict__ q, const float* __restrict__ k,
    const float* __restrict__ v, const unsigned long long* __restrict__ mask,
    float* __restrict__ out) {
  __shared__ float Qs[64][64];       // broadcast reads only
  __shared__ float Ks[64][64];       // swizzled: [r][d ^ (r&31)]
  __shared__ float Vs[64][64];       // read [j][lane]: conflict-free
  __shared__ float Ps[4][16][64];    // per-wave P, written [i][lane]

  const int bh = blockIdx.x;   // b*H + h
  const int qt = blockIdx.y;   // q tile 0..15
  const int b = bh >> 4;
  const int tid = threadIdx.x;
  const int wave = tid >> 6, lane = tid & 63;
  const size_t base = (size_t)bh * T_ * D_;

  for (int idx = tid; idx < 64 * 64; idx += 256) {
    const int r = idx >> 6, d = idx & 63;
    Qs[r][d] = q[base + (size_t)(qt * 64 + r) * D_ + d];
  }

  float m[16], l[16], O[16];
#pragma unroll
  for (int i = 0; i < 16; i++) { m[i] = -INFINITY; l[i] = 0.0f; O[i] = 0.0f; }
  const int i0 = wave * 16;

  for (int kt = 0; kt <= qt; kt++) {
    __syncthreads();  // previous tile's LDS reads done
    for (int idx = tid; idx < 64 * 64; idx += 256) {
      const int r = idx >> 6, d = idx & 63;
      const size_t g = base + (size_t)(kt * 64 + r) * D_ + d;
      Ks[r][d ^ (r & 31)] = k[g];
      Vs[r][d] = v[g];
    }
    __syncthreads();

    // ---- scores: S[i][lane] = q_i . k_lane
    float S[16];
#pragma unroll
    for (int i = 0; i < 16; i++) S[i] = 0.0f;
    for (int d = 0; d < 64; d++) {
      const float kd = Ks[lane][d ^ (lane & 31)];  // 2-way (free)
#pragma unroll
      for (int i = 0; i < 16; i++) S[i] += Qs[i0 + i][d] * kd;  // bcast
    }

    // ---- mask + online softmax (per row)
#pragma unroll
    for (int i = 0; i < 16; i++) {
      const int ig = qt * 64 + i0 + i;
      const unsigned long long w = mask[((size_t)(b * T_ + ig) << 4) + kt];
      const bool ok = (w >> lane) & 1ull;
      const float s = ok ? S[i] * 0.125f : -INFINITY;  // scale = D^-0.5

      float mt = s;
#pragma unroll
      for (int off = 32; off; off >>= 1) mt = fmaxf(mt, __shfl_xor(mt, off));
      const float mnew = fmaxf(m[i], mt);

      float p, corr;
      if (mnew == -INFINITY) {        // whole tile masked, nothing yet
        p = 0.0f; corr = 1.0f;
      } else {
        corr = expf(m[i] - mnew);     // m=-inf -> 0 (correct)
        p = expf(s - mnew);           // s=-inf -> 0
      }
      float ps = p;
#pragma unroll
      for (int off = 32; off; off >>= 1) ps += __shfl_xor(ps, off);
      l[i] = l[i] * corr + ps;
      m[i] = mnew;
      O[i] *= corr;
      Ps[wave][i][lane] = p;          // per-wave region: no cross-wave sync
    }

    // ---- PV: lane = d
    for (int j = 0; j < 64; j++) {
      const float vj = Vs[j][lane];
#pragma unroll
      for (int i = 0; i < 16; i++) O[i] += Ps[wave][i][j] * vj;  // bcast P
    }
  }

#pragma unroll
  for (int i = 0; i < 16; i++) {
    const int ig = qt * 64 + i0 + i;
    out[base + (size_t)ig * D_ + lane] = O[i] / l[i];
  }
}

extern "C" void kernel_launch(void* const* d_in, const int* in_sizes, int n_in,
                              void* d_out, int out_size, void* d_ws, size_t ws_size,
                              hipStream_t stream) {
  const float* q  = (const float*)d_in[0];
  const float* k  = (const float*)d_in[1];
  const float* v  = (const float*)d_in[2];
  const float* W1 = (const float*)d_in[3];
  const float* b1 = (const float*)d_in[4];
  const float* W2 = (const float*)d_in[5];
  const float* b2 = (const float*)d_in[6];
  float* out = (float*)d_out;

  // ws layout: probs [B*T*16] f32 (256 KB) | mask [B*T*16] u64 (512 KB)
  float* probs = (float*)d_ws;
  unsigned long long* mask =
      (unsigned long long*)((char*)d_ws + (size_t)B_ * T_ * NB * sizeof(float));

  router_kernel<<<512, 256, 0, stream>>>(k, W1, b1, W2, b2, probs);
  mask_kernel<<<B_ * T_, 256, 0, stream>>>(probs, mask);
  attn_kernel<<<dim3(B_ * H_, T_ / 64), 256, 0, stream>>>(q, k, v, mask, out);
}